// Round 6
// baseline (173.122 us; speedup 1.0000x reference)
//
#include <hip/hip_runtime.h>

// ---------------------------------------------------------------------------
// BasicTransformerBlock cross-frame attention, MI355X (gfx950)  — round 6
// B=16, S=1024, C=320, H=8, D=40, b=1, key frame = k
// cvt(+Vt pad zero) -> projQ -> projKV -> attn(KVBLK=128, double-buffered
// global_load_lds staging, key-permuted K LDS, in-register P) -> projO.
// Proj: 2-phase dbuf pipeline, 64x64 tiles.
// ---------------------------------------------------------------------------

typedef short bf16x8 __attribute__((ext_vector_type(8)));
typedef float f32x4 __attribute__((ext_vector_type(4)));

constexpr int SEQ = 1024;
constexpr int CH  = 320;
constexpr int NH  = 8;
constexpr int HD  = 40;
constexpr int KPD = 48;
constexpr int HS_N = 16384 * CH;      // 5,242,880
constexpr int W_N  = CH * CH;         // 102,400
constexpr int NCVT = (HS_N + 4 * W_N) / 2048;   // 2760 blocks
constexpr int NPAD = 32;                         // Vt pad-zero blocks
// scale = 1/sqrt(40) folded with log2(e) (softmax uses exp2)
constexpr float QSCALE = 0.15811388300841897f * 1.4426950408889634f;

__device__ __forceinline__ unsigned cvtpk(float lo, float hi) {
  unsigned r;
  asm("v_cvt_pk_bf16_f32 %0, %1, %2" : "=v"(r) : "v"(lo), "v"(hi));
  return r;
}
__device__ __forceinline__ unsigned short bf1(float v) {
  return (unsigned short)cvtpk(v, v);
}

#define GLOAD16(gp, lp)                                                        \
  __builtin_amdgcn_global_load_lds(                                            \
      (const __attribute__((address_space(1))) void*)(gp),                     \
      (__attribute__((address_space(3))) void*)(lp), 16, 0, 0)

// ---------------------------------------------------------------------------
// convert pass: hs (f32->bf16), Wq*QSCALE, Wk, Wv, Wo; plus zero Vt[d=40..47]
// ---------------------------------------------------------------------------
__global__ __launch_bounds__(256)
void cvt_kernel(const float* __restrict__ hs, const float* __restrict__ Wq,
                const float* __restrict__ Wk, const float* __restrict__ Wv,
                const float* __restrict__ Wo, unsigned short* __restrict__ hsb,
                unsigned short* __restrict__ wqb, unsigned short* __restrict__ wkb,
                unsigned short* __restrict__ wvb, unsigned short* __restrict__ wob,
                unsigned short* __restrict__ Vt) {
  if (blockIdx.x >= NCVT) {
    // zero Vt pad rows: 8 heads x 8 rows (40..47) x 1024 cols = 65536 shorts
    const int off = (blockIdx.x - NCVT) * 2048 + threadIdx.x * 8;
    const int h = off >> 13, inner = off & 8191;
    *(bf16x8*)(Vt + (size_t)(h * KPD + 40 + (inner >> 10)) * SEQ + (inner & 1023)) =
        (bf16x8){};
    return;
  }
  const int i8 = (blockIdx.x * 256 + threadIdx.x) * 8;
  const float* src; unsigned short* dst; int off; float sc = 1.f;
  if (i8 < HS_N) { src = hs; dst = hsb; off = i8; }
  else {
    int j = i8 - HS_N;
    if (j < W_N)            { src = Wq; dst = wqb; off = j;           sc = QSCALE; }
    else if (j < 2 * W_N)   { src = Wk; dst = wkb; off = j - W_N; }
    else if (j < 3 * W_N)   { src = Wv; dst = wvb; off = j - 2 * W_N; }
    else                    { src = Wo; dst = wob; off = j - 3 * W_N; }
  }
  float4 f0 = *(const float4*)(src + off);
  float4 f1 = *(const float4*)(src + off + 4);
  union { bf16x8 v; unsigned u[4]; } o;
  o.u[0] = cvtpk(f0.x * sc, f0.y * sc);
  o.u[1] = cvtpk(f0.z * sc, f0.w * sc);
  o.u[2] = cvtpk(f1.x * sc, f1.y * sc);
  o.u[3] = cvtpk(f1.z * sc, f1.w * sc);
  *(bf16x8*)(dst + off) = o.v;
}

// ---------------------------------------------------------------------------
// bf16 projection GEMM, tile 64x64, BK=64, 4 waves (2x2), 2-phase dbuf:
// issue step t+1's global_load_lds before computing step t (one barrier/step).
// XOR-swizzled LDS (128B rows, chunk ^= row&7) via pre-swizzled source.
// MODE 0: out bf16 [m][CH]   MODE 1: z=0 Kp [h][s][KPD] / z=1 Vt [h][KPD][s]
// MODE 3: out f32 [m][CH] + bias
// ---------------------------------------------------------------------------
__device__ __forceinline__ bf16x8 lds_frag(const unsigned short* T, int row, int lc) {
  return *(const bf16x8*)((const char*)T + row * 128 + ((lc ^ (row & 7)) << 4));
}

template <int MODE>
__global__ __launch_bounds__(256)
void proj4(const unsigned short* __restrict__ A, const unsigned short* __restrict__ W,
           void* __restrict__ outp, const float* __restrict__ bias,
           const int* __restrict__ kptr, const unsigned short* __restrict__ W2,
           void* __restrict__ out2) {
  __shared__ unsigned short Al[2][64][64];
  __shared__ unsigned short Bl[2][64][64];

  const int tid = threadIdx.x;
  const int w = tid >> 6, l = tid & 63, g = l >> 4, c = l & 15;
  const int wm = w >> 1, wn = w & 1;
  const int mb = blockIdx.x, nb = blockIdx.y;

  const unsigned short* Wp = W;
  void* op = outp;
  bool isV = false;
  if (MODE == 1 && blockIdx.z == 1) { Wp = W2; op = out2; isV = true; }
  const int rowbase = (MODE == 1) ? kptr[0] * SEQ : 0;

  // staging: rows sr, sr+32; phys chunk pc; logical chunk lc = pc ^ (sr&7)
  // ((sr+32)&7 == sr&7 so one lc per thread)
  const int sr = tid >> 3, pc = tid & 7;
  const int lc = pc ^ (sr & 7);
  const unsigned short* aBase = A + (size_t)(rowbase + mb * 64) * CH + lc * 8;
  const unsigned short* wBase = Wp + (size_t)(nb * 64) * CH + lc * 8;

  f32x4 acc[2][2] = {};

#define PSTAGE(buf, kb)                                                        \
  {                                                                            \
    GLOAD16(aBase + (size_t)sr * CH + (kb), &Al[buf][0][0] + tid * 8);         \
    GLOAD16(aBase + (size_t)(sr + 32) * CH + (kb),                             \
            &Al[buf][0][0] + (tid + 256) * 8);                                 \
    GLOAD16(wBase + (size_t)sr * CH + (kb), &Bl[buf][0][0] + tid * 8);         \
    GLOAD16(wBase + (size_t)(sr + 32) * CH + (kb),                             \
            &Bl[buf][0][0] + (tid + 256) * 8);                                 \
  }

  PSTAGE(0, 0);
  __syncthreads();                       // drain: step 0 staged

#pragma unroll
  for (int t = 0; t < 5; ++t) {
    if (t < 4) PSTAGE((t + 1) & 1, (t + 1) * 64);
    const unsigned short* A_ = &Al[t & 1][0][0];
    const unsigned short* B_ = &Bl[t & 1][0][0];
#pragma unroll
    for (int kc = 0; kc < 2; ++kc) {
      bf16x8 a0 = lds_frag(A_, wm * 32 + c,      kc * 4 + g);
      bf16x8 a1 = lds_frag(A_, wm * 32 + 16 + c, kc * 4 + g);
      bf16x8 b0 = lds_frag(B_, wn * 32 + c,      kc * 4 + g);
      bf16x8 b1 = lds_frag(B_, wn * 32 + 16 + c, kc * 4 + g);
      acc[0][0] = __builtin_amdgcn_mfma_f32_16x16x32_bf16(a0, b0, acc[0][0], 0, 0, 0);
      acc[0][1] = __builtin_amdgcn_mfma_f32_16x16x32_bf16(a0, b1, acc[0][1], 0, 0, 0);
      acc[1][0] = __builtin_amdgcn_mfma_f32_16x16x32_bf16(a1, b0, acc[1][0], 0, 0, 0);
      acc[1][1] = __builtin_amdgcn_mfma_f32_16x16x32_bf16(a1, b1, acc[1][1], 0, 0, 0);
    }
    __syncthreads();                     // stage t+1 complete; reads of buf t done
  }
#undef PSTAGE

  // epilogue: D lane (g,c) reg r -> row = g*4+r, col = c
#pragma unroll
  for (int i = 0; i < 2; ++i)
#pragma unroll
    for (int j = 0; j < 2; ++j)
#pragma unroll
      for (int r = 0; r < 4; ++r) {
        const int m = mb * 64 + wm * 32 + i * 16 + g * 4 + r;
        const int n = nb * 64 + wn * 32 + j * 16 + c;
        const float v = acc[i][j][r];
        if (MODE == 0) {
          ((unsigned short*)op)[(size_t)m * CH + n] = bf1(v);
        } else if (MODE == 1) {
          const int h = n / HD, d = n % HD;
          if (!isV)
            ((unsigned short*)op)[(size_t)(h * SEQ + m) * KPD + d] = bf1(v);
          else
            ((unsigned short*)op)[(size_t)(h * KPD + d) * SEQ + m] = bf1(v);
        } else {
          ((float*)op)[(size_t)m * CH + n] = v + bias[n];
        }
      }
}

// ---------------------------------------------------------------------------
// Flash attention, KVBLK=128, double-buffered. Grid 1024 = (qt 0..7)|(bh<<3).
// Block 512 = 8 waves; wave owns 16 q-rows (lane c = q-row).
// K staged at permuted slot s (per 64-group): phys key = (s&35)|((s&12)<<1)|((s&16)>>2)
// => after softmax the lane's p regs ARE the PV B-fragment (P never leaves regs).
// Staging via global_load_lds (LDS dest = base + tid*16, per-lane global src).
// K rows 128B chunk^=(slot&7); V rows 256B chunk^=(row&15): conflict-free reads.
// One barrier per tile; DMA of tile t+1 overlaps compute of tile t.
// ---------------------------------------------------------------------------
__global__ __launch_bounds__(512)
void attn6(const unsigned short* __restrict__ Qs,
           const unsigned short* __restrict__ Kp,
           const unsigned short* __restrict__ Vt,
           unsigned short* __restrict__ AO) {
  __shared__ unsigned short Klds[2][128][64];   // 2 x 16 KB  [slot][d]
  __shared__ unsigned short Vlds[2][64][128];   // 2 x 16 KB  [d][key] (rows 48..63 junk)

  const int tid = threadIdx.x;
  const int w = tid >> 6, l = tid & 63, g = l >> 4, c = l & 15;
  const int qt = blockIdx.x & 7, bh = blockIdx.x >> 3;
  const int b = bh >> 3, h = bh & 7;
  const int qrow0 = qt * 128 + w * 16;

  // ---- K staging: slot_i = (tid>>3) + i*64, pc = tid&7, lc = pc^(slot&7)
  const int slot = tid >> 3, pc = tid & 7;
  const int lcK = pc ^ (slot & 7);
  const int key0 = (slot & 35) | ((slot & 12) << 1) | ((slot & 16) >> 2);
  const unsigned short* gK0 = Kp + (size_t)((h << 10) + key0) * KPD + lcK * 8;
  const unsigned short* gK1 = gK0 + 64 * KPD;
  // ---- V staging: row_j = (tid>>4) + j*32, pos = tid&15, lc = pos^(row&15)
  const int vrow = tid >> 4, vpos = tid & 15;
  const int lcV = vpos ^ (vrow & 15);
  const unsigned short* gV0 = Vt + (size_t)(h * KPD + vrow) * SEQ + lcV * 8;
  const unsigned short* gV1 = Vt + (size_t)(h * KPD + vrow + 32) * SEQ + lcV * 8;
  char* dK = (char*)&Klds[0][0][0] + tid * 16;
  char* dV = (char*)&Vlds[0][0][0] + tid * 16;

#define ASTAGE(bufoff)                                                         \
  {                                                                            \
    GLOAD16(gK0, dK + (bufoff)); GLOAD16(gK1, dK + (bufoff) + 8192);           \
    GLOAD16(gV0, dV + (bufoff)); GLOAD16(gV1, dV + (bufoff) + 8192);           \
    gK0 += 128 * KPD; gK1 += 128 * KPD; gV0 += 128; gV1 += 128;                \
  }

  ASTAGE(0);                             // tile 0 -> buffer 0

  // ---- Q fragments (B-operand: lane holds Q[qrow=c][d-chunk g])
  const unsigned short* qp = Qs + (size_t)(b * SEQ + qrow0 + c) * CH + h * HD;
  bf16x8 aq0 = *(const bf16x8*)(qp + g * 8);
  bf16x8 aq1 = {};
  if (g == 0) aq1 = *(const bf16x8*)(qp + 32);

  f32x4 o0 = {}, o1 = {}, o2 = {};
  float m = -3e38f, lsum = 0.f;

  const int sw = c & 7;

  for (int kt = 0; kt < 8; ++kt) {
    const int cur = (kt & 1) << 14;      // byte offset of current buffer
    __syncthreads();                     // drains DMA -> buf cur ready; prior
                                         // readers of the other buf all done
    if (kt < 7) ASTAGE(16384 - cur);     // DMA next tile into other buffer

    const char* kROb = (const char*)&Klds[0][0][0] + cur + c * 128;
    const char* vROb = (const char*)&Vlds[0][0][0] + cur + c * 256;

    // ---- S^T = K * Q^T : 8 jt-groups x 2 MFMA (d 0..31, d 32..39)
    f32x4 p[8];
    __builtin_amdgcn_s_setprio(1);
#pragma unroll
    for (int jt = 0; jt < 8; ++jt) {
      const char* kr = kROb + jt * 2048;
      bf16x8 ak0 = *(const bf16x8*)(kr + ((g ^ sw) << 4));
      bf16x8 ak1 = *(const bf16x8*)(kr + ((4 ^ sw) << 4));  // real d32..39 data;
      f32x4 s = __builtin_amdgcn_mfma_f32_16x16x32_bf16(ak0, aq0, (f32x4){}, 0, 0, 0);
      p[jt] = __builtin_amdgcn_mfma_f32_16x16x32_bf16(ak1, aq1, s, 0, 0, 0);
    }                                    // g>0 lanes: aq1=0 annihilates dup data
    __builtin_amdgcn_s_setprio(0);

    // ---- per-lane softmax (lane owns q-row c; partners at lanes ^16, ^32)
    float vmax = -3e38f;
#pragma unroll
    for (int jt = 0; jt < 8; ++jt)
      vmax = fmaxf(vmax, fmaxf(fmaxf(p[jt][0], p[jt][1]), fmaxf(p[jt][2], p[jt][3])));
    vmax = fmaxf(vmax, __shfl_xor(vmax, 16));
    vmax = fmaxf(vmax, __shfl_xor(vmax, 32));
    if (__any(vmax > m + 8.f)) {         // defer-max: rescale only on growth
      const float mn = fmaxf(m, vmax);
      const float al = exp2f(m - mn);
      m = mn; lsum *= al;
      o0 *= al; o1 *= al; o2 *= al;
    }
    float rs = 0.f;
#pragma unroll
    for (int jt = 0; jt < 8; ++jt)
#pragma unroll
      for (int r = 0; r < 4; ++r) { p[jt][r] = exp2f(p[jt][r] - m); rs += p[jt][r]; }
    rs += __shfl_xor(rs, 16);
    rs += __shfl_xor(rs, 32);
    lsum += rs;

    // ---- O^T += V^T * P^T  (A = Vlds row dt*16+c, key-chunk kc*4+g; B = p regs)
    __builtin_amdgcn_s_setprio(1);
#pragma unroll
    for (int kc = 0; kc < 4; ++kc) {
      union { bf16x8 v; unsigned u[4]; } pb;
      pb.u[0] = cvtpk(p[2 * kc][0], p[2 * kc][1]);
      pb.u[1] = cvtpk(p[2 * kc][2], p[2 * kc][3]);
      pb.u[2] = cvtpk(p[2 * kc + 1][0], p[2 * kc + 1][1]);
      pb.u[3] = cvtpk(p[2 * kc + 1][2], p[2 * kc + 1][3]);
      const int ch = ((kc * 4 + g) ^ c) << 4;
      bf16x8 av;
      av = *(const bf16x8*)(vROb + ch);
      o0 = __builtin_amdgcn_mfma_f32_16x16x32_bf16(av, pb.v, o0, 0, 0, 0);
      av = *(const bf16x8*)(vROb + 4096 + ch);
      o1 = __builtin_amdgcn_mfma_f32_16x16x32_bf16(av, pb.v, o1, 0, 0, 0);
      av = *(const bf16x8*)(vROb + 8192 + ch);
      o2 = __builtin_amdgcn_mfma_f32_16x16x32_bf16(av, pb.v, o2, 0, 0, 0);
    }
    __builtin_amdgcn_s_setprio(0);
  }
#undef ASTAGE

  // ---- epilogue: lane owns q-row c; O^T row d = dt*16 + g*4 + r
  const float inv = 1.0f / lsum;
  unsigned short* orow = AO + (size_t)(b * SEQ + qrow0 + c) * CH + h * HD;
  union { uint2 q; unsigned u[2]; } st;
  st.u[0] = cvtpk(o0[0] * inv, o0[1] * inv);
  st.u[1] = cvtpk(o0[2] * inv, o0[3] * inv);
  *(uint2*)(orow + g * 4) = st.q;
  st.u[0] = cvtpk(o1[0] * inv, o1[1] * inv);
  st.u[1] = cvtpk(o1[2] * inv, o1[3] * inv);
  *(uint2*)(orow + 16 + g * 4) = st.q;
  if (g < 2) {
    st.u[0] = cvtpk(o2[0] * inv, o2[1] * inv);
    st.u[1] = cvtpk(o2[2] * inv, o2[3] * inv);
    *(uint2*)(orow + 32 + g * 4) = st.q;
  }
}

// ---------------------------------------------------------------------------
extern "C" void kernel_launch(void* const* d_in, const int* in_sizes, int n_in,
                              void* d_out, int out_size, void* d_ws, size_t ws_size,
                              hipStream_t stream) {
  const float* hs = (const float*)d_in[0];
  const float* Wq = (const float*)d_in[1];
  const float* Wk = (const float*)d_in[2];
  const float* Wv = (const float*)d_in[3];
  const float* Wo = (const float*)d_in[4];
  const float* bo = (const float*)d_in[5];
  const int* kptr = (const int*)d_in[7];
  float* out = (float*)d_out;

  unsigned short* hsb = (unsigned short*)d_ws;
  unsigned short* wqb = hsb + HS_N;
  unsigned short* wkb = wqb + W_N;
  unsigned short* wvb = wkb + W_N;
  unsigned short* wob = wvb + W_N;
  unsigned short* Qs  = wob + W_N;
  unsigned short* Kp  = Qs + HS_N;                 // [8][1024][48]
  unsigned short* Vt  = Kp + NH * SEQ * KPD;       // [8][48][1024]
  unsigned short* AO  = Vt + NH * KPD * SEQ;       // [16384][320]

  dim3 blk(256);
  cvt_kernel<<<dim3(NCVT + NPAD), blk, 0, stream>>>(
      hs, Wq, Wk, Wv, Wo, hsb, wqb, wkb, wvb, wob, Vt);
  proj4<0><<<dim3(256, 5), blk, 0, stream>>>(hsb, wqb, Qs, nullptr, nullptr, nullptr, nullptr);
  proj4<1><<<dim3(16, 5, 2), blk, 0, stream>>>(hsb, wkb, Kp, nullptr, kptr, wvb, Vt);
  attn6<<<dim3(1024), dim3(512), 0, stream>>>(Qs, Kp, Vt, AO);
  proj4<3><<<dim3(256, 5), blk, 0, stream>>>(AO, wob, out, bo, nullptr, nullptr, nullptr);
}

// Round 8
// 164.607 us; speedup vs baseline: 1.0517x; 1.0517x over previous
//
#include <hip/hip_runtime.h>

// ---------------------------------------------------------------------------
// BasicTransformerBlock cross-frame attention, MI355X (gfx950)  — round 8
// (= round-7 design, re-audited; previous submission never ran: GPU timeout)
// B=16, S=1024, C=320, H=8, D=40, b=1, key frame = k
// 3 kernels: qkv_proj (f32 in, fused cvt) -> attn (fixed-max softmax, lsum via
// ones-column MFMA) -> o_proj.
// ---------------------------------------------------------------------------

typedef short bf16x8 __attribute__((ext_vector_type(8)));
typedef float f32x4 __attribute__((ext_vector_type(4)));

constexpr int SEQ = 1024;
constexpr int CH  = 320;
constexpr int NH  = 8;
constexpr int HD  = 40;
constexpr int KPD = 48;
constexpr int HS_N = 16384 * CH;
// scale = 1/sqrt(40) folded with log2(e) (softmax uses exp2)
constexpr float QSCALE = 0.15811388300841897f * 1.4426950408889634f;
constexpr float MSUB = 8.0f;   // fixed softmax "max": scores |s|~<2, exact shift

__device__ __forceinline__ unsigned cvtpk(float lo, float hi) {
  unsigned r;
  asm("v_cvt_pk_bf16_f32 %0, %1, %2" : "=v"(r) : "v"(lo), "v"(hi));
  return r;
}
__device__ __forceinline__ unsigned short bf1(float v) {
  return (unsigned short)cvtpk(v, v);
}

#define GLOAD16(gp, lp)                                                        \
  __builtin_amdgcn_global_load_lds(                                            \
      (const __attribute__((address_space(1))) void*)(gp),                     \
      (__attribute__((address_space(3))) void*)(lp), 16, 0, 0)

// swizzled LDS fragment read: rows 128B, phys chunk = logical ^ (row&7)
__device__ __forceinline__ bf16x8 lds_frag(const unsigned short* T, int row, int lc) {
  return *(const bf16x8*)((const char*)T + row * 128 + ((lc ^ (row & 7)) << 4));
}

// ---------------------------------------------------------------------------
// Fused QKV projection, f32 inputs, tile 64x64, BK=64, 4 waves (2x2).
// Grid 1440: bx<1280 Q (mb=bx/5,nb=bx%5); 1280..1359 K; 1360..1439 V.
// Reg-stage f32 -> cvt_pk -> swizzled ds_write. Loads for step t+1 issued
// right after barrier B of step t (overlap compute).
// Q: out bf16 [m][CH] * QSCALE.  K: Kp [h][s][KPD].  V: Vt [h][KPD][s],
// V-blocks with nb==0 also init Vt pad rows (d=40 -> 1.0, d=41..47 -> 0).
// ---------------------------------------------------------------------------
__global__ __launch_bounds__(256)
void qkv_proj(const float* __restrict__ hs, const float* __restrict__ Wq,
              const float* __restrict__ Wk, const float* __restrict__ Wv,
              const int* __restrict__ kptr,
              unsigned short* __restrict__ Qs, unsigned short* __restrict__ Kp,
              unsigned short* __restrict__ Vt) {
  __shared__ unsigned short Al[64][64];
  __shared__ unsigned short Bl[64][64];

  const int tid = threadIdx.x;
  const int w = tid >> 6, l = tid & 63, g = l >> 4, c = l & 15;
  const int wm = w >> 1, wn = w & 1;

  const int bx = blockIdx.x;
  int mode, mb, nb, rowbase;
  const float* W;
  if (bx < 1280)      { mode = 0; mb = bx / 5;          nb = bx - mb * 5;          rowbase = 0;              W = Wq; }
  else if (bx < 1360) { int t = bx - 1280; mode = 1; mb = t / 5; nb = t - mb * 5;  rowbase = kptr[0] * SEQ;  W = Wk; }
  else                { int t = bx - 1360; mode = 2; mb = t / 5; nb = t - mb * 5;  rowbase = kptr[0] * SEQ;  W = Wv; }

  // staging: rows sr, sr+32 ((sr+32)&7 == sr&7); 8 floats at col ch*8
  const int sr = tid >> 3, ch = tid & 7;
  const int pc = ch ^ (sr & 7);
  const float* aB = hs + (size_t)(rowbase + mb * 64) * CH + ch * 8;
  const float* wB = W + (size_t)(nb * 64) * CH + ch * 8;
  unsigned short* dA0 = &Al[sr][pc * 8];
  unsigned short* dA1 = &Al[sr + 32][pc * 8];
  unsigned short* dB0 = &Bl[sr][pc * 8];
  unsigned short* dB1 = &Bl[sr + 32][pc * 8];

  float4 ra0, ra1, ra2, ra3, rw0, rw1, rw2, rw3;
#define QLOAD(kb)                                                              \
  {                                                                            \
    ra0 = *(const float4*)(aB + (size_t)sr * CH + (kb));                       \
    ra1 = *(const float4*)(aB + (size_t)sr * CH + (kb) + 4);                   \
    ra2 = *(const float4*)(aB + (size_t)(sr + 32) * CH + (kb));                \
    ra3 = *(const float4*)(aB + (size_t)(sr + 32) * CH + (kb) + 4);            \
    rw0 = *(const float4*)(wB + (size_t)sr * CH + (kb));                       \
    rw1 = *(const float4*)(wB + (size_t)sr * CH + (kb) + 4);                   \
    rw2 = *(const float4*)(wB + (size_t)(sr + 32) * CH + (kb));                \
    rw3 = *(const float4*)(wB + (size_t)(sr + 32) * CH + (kb) + 4);            \
  }
#define CVW(dst, f0, f1)                                                       \
  {                                                                            \
    union { bf16x8 v; unsigned u[4]; } pk_;                                    \
    pk_.u[0] = cvtpk(f0.x, f0.y); pk_.u[1] = cvtpk(f0.z, f0.w);                \
    pk_.u[2] = cvtpk(f1.x, f1.y); pk_.u[3] = cvtpk(f1.z, f1.w);                \
    *(bf16x8*)(dst) = pk_.v;                                                   \
  }

  f32x4 acc[2][2] = {};
  QLOAD(0);
#pragma unroll
  for (int t = 0; t < 5; ++t) {
    __syncthreads();                     // prior compute done reading LDS
    CVW(dA0, ra0, ra1); CVW(dA1, ra2, ra3);
    CVW(dB0, rw0, rw1); CVW(dB1, rw2, rw3);
    __syncthreads();                     // tile visible
    if (t < 4) QLOAD((t + 1) * 64);      // issue next loads, overlap compute
#pragma unroll
    for (int kc = 0; kc < 2; ++kc) {
      bf16x8 a0 = lds_frag(&Al[0][0], wm * 32 + c,      kc * 4 + g);
      bf16x8 a1 = lds_frag(&Al[0][0], wm * 32 + 16 + c, kc * 4 + g);
      bf16x8 b0 = lds_frag(&Bl[0][0], wn * 32 + c,      kc * 4 + g);
      bf16x8 b1 = lds_frag(&Bl[0][0], wn * 32 + 16 + c, kc * 4 + g);
      acc[0][0] = __builtin_amdgcn_mfma_f32_16x16x32_bf16(a0, b0, acc[0][0], 0, 0, 0);
      acc[0][1] = __builtin_amdgcn_mfma_f32_16x16x32_bf16(a0, b1, acc[0][1], 0, 0, 0);
      acc[1][0] = __builtin_amdgcn_mfma_f32_16x16x32_bf16(a1, b0, acc[1][0], 0, 0, 0);
      acc[1][1] = __builtin_amdgcn_mfma_f32_16x16x32_bf16(a1, b1, acc[1][1], 0, 0, 0);
    }
  }
#undef QLOAD
#undef CVW

  // epilogue: D lane (g,c) reg r -> row = g*4+r, col = c
#pragma unroll
  for (int i = 0; i < 2; ++i)
#pragma unroll
    for (int j = 0; j < 2; ++j)
#pragma unroll
      for (int r = 0; r < 4; ++r) {
        const int m = mb * 64 + wm * 32 + i * 16 + g * 4 + r;
        const int n = nb * 64 + wn * 32 + j * 16 + c;
        const float v = acc[i][j][r];
        if (mode == 0) {
          Qs[(size_t)m * CH + n] = bf1(v * QSCALE);
        } else {
          const int h = n / HD, d = n - h * HD;
          if (mode == 1) Kp[(size_t)(h * SEQ + m) * KPD + d] = bf1(v);
          else           Vt[(size_t)(h * KPD + d) * SEQ + m] = bf1(v);
        }
      }

  // V pad init: rows d=40 (ones, for lsum-via-MFMA) and 41..47 (zeros)
  if (mode == 2 && nb == 0) {
    const int s0 = mb * 64;
    const int hh = tid >> 5, rem = tid & 31;
    const int dd = 40 + (rem >> 2), sb = (rem & 3) * 16;
    const short val = (dd == 40) ? (short)0x3F80 : (short)0;
    bf16x8 vv = {val, val, val, val, val, val, val, val};
    unsigned short* p = Vt + (size_t)(hh * KPD + dd) * SEQ + s0 + sb;
    *(bf16x8*)p = vv;
    *(bf16x8*)(p + 8) = vv;
  }
}

// ---------------------------------------------------------------------------
// Flash attention, KVBLK=128, double-buffered gload_lds staging.
// Grid 1024 = (qt 0..7)|(bh<<3). Block 512 = 8 waves; wave owns 16 q-rows.
// Fixed-max softmax: QK MFMA C-init = -8; p = exp2(s); no reductions.
// lsum = column d=40 of O^T (V ones-row), read via one shfl at epilogue.
// K staged at permuted slot s (per 64-group): phys key = (s&35)|((s&12)<<1)|((s&16)>>2)
// => lane's p regs ARE the PV B-fragment (P never leaves registers).
// ---------------------------------------------------------------------------
__global__ __launch_bounds__(512)
void attn7(const unsigned short* __restrict__ Qs,
           const unsigned short* __restrict__ Kp,
           const unsigned short* __restrict__ Vt,
           unsigned short* __restrict__ AO) {
  __shared__ unsigned short Klds[2][128][64];   // 2 x 16 KB  [slot][d]
  __shared__ unsigned short Vlds[2][64][128];   // 2 x 16 KB  [d][key]

  const int tid = threadIdx.x;
  const int w = tid >> 6, l = tid & 63, g = l >> 4, c = l & 15;
  const int qt = blockIdx.x & 7, bh = blockIdx.x >> 3;
  const int b = bh >> 3, h = bh & 7;
  const int qrow0 = qt * 128 + w * 16;

  // K staging: slot_i = (tid>>3)+i*64, pc = tid&7, lc = pc^(slot&7)
  const int slot = tid >> 3, pc = tid & 7;
  const int lcK = pc ^ (slot & 7);
  const int key0 = (slot & 35) | ((slot & 12) << 1) | ((slot & 16) >> 2);
  const unsigned short* gK0 = Kp + (size_t)((h << 10) + key0) * KPD + lcK * 8;
  const unsigned short* gK1 = gK0 + 64 * KPD;
  // V staging: row_j = (tid>>4)+j*32, pos = tid&15, lc = pos^(row&15)
  const int vrow = tid >> 4, vpos = tid & 15;
  const int lcV = vpos ^ (vrow & 15);
  const unsigned short* gV0 = Vt + (size_t)(h * KPD + vrow) * SEQ + lcV * 8;
  const unsigned short* gV1 = Vt + (size_t)(h * KPD + vrow + 32) * SEQ + lcV * 8;
  char* dK = (char*)&Klds[0][0][0] + tid * 16;
  char* dV = (char*)&Vlds[0][0][0] + tid * 16;

#define ASTAGE(bufoff)                                                         \
  {                                                                            \
    GLOAD16(gK0, dK + (bufoff)); GLOAD16(gK1, dK + (bufoff) + 8192);           \
    GLOAD16(gV0, dV + (bufoff)); GLOAD16(gV1, dV + (bufoff) + 8192);           \
    gK0 += 128 * KPD; gK1 += 128 * KPD; gV0 += 128; gV1 += 128;                \
  }

  ASTAGE(0);                             // tile 0 -> buffer 0

  // Q fragments (B-operand: lane holds Q[qrow=c][d-chunk g])
  const unsigned short* qp = Qs + (size_t)(b * SEQ + qrow0 + c) * CH + h * HD;
  bf16x8 aq0 = *(const bf16x8*)(qp + g * 8);
  bf16x8 aq1 = {};
  if (g == 0) aq1 = *(const bf16x8*)(qp + 32);

  f32x4 o0 = {}, o1 = {}, o2 = {};
  const f32x4 minit = {-MSUB, -MSUB, -MSUB, -MSUB};
  const int sw = c & 7;

  for (int kt = 0; kt < 8; ++kt) {
    const int cur = (kt & 1) << 14;
    __syncthreads();                     // drains DMA -> buf cur ready
    if (kt < 7) ASTAGE(16384 - cur);     // DMA next tile into other buffer

    const char* kROb = (const char*)&Klds[0][0][0] + cur + c * 128;
    const char* vROb = (const char*)&Vlds[0][0][0] + cur + c * 256;

    // S^T - 8 = K * Q^T + (-8) : 8 jt-groups x 2 MFMA
    f32x4 p[8];
    __builtin_amdgcn_s_setprio(1);
#pragma unroll
    for (int jt = 0; jt < 8; ++jt) {
      const char* kr = kROb + jt * 2048;
      bf16x8 ak0 = *(const bf16x8*)(kr + ((g ^ sw) << 4));
      bf16x8 ak1 = *(const bf16x8*)(kr + ((4 ^ sw) << 4));   // g>0: aq1=0
      f32x4 s = __builtin_amdgcn_mfma_f32_16x16x32_bf16(ak0, aq0, minit, 0, 0, 0);
      p[jt] = __builtin_amdgcn_mfma_f32_16x16x32_bf16(ak1, aq1, s, 0, 0, 0);
    }
    __builtin_amdgcn_s_setprio(0);

    // p = exp2(s - 8): exact softmax shift (scores bounded ~|2|); no reductions
#pragma unroll
    for (int jt = 0; jt < 8; ++jt)
#pragma unroll
      for (int r = 0; r < 4; ++r) p[jt][r] = exp2f(p[jt][r]);

    // O^T += V^T * P^T  (A = Vlds row dt*16+c, key-chunk kc*4+g; B = p regs)
    __builtin_amdgcn_s_setprio(1);
#pragma unroll
    for (int kc = 0; kc < 4; ++kc) {
      union { bf16x8 v; unsigned u[4]; } pb;
      pb.u[0] = cvtpk(p[2 * kc][0], p[2 * kc][1]);
      pb.u[1] = cvtpk(p[2 * kc][2], p[2 * kc][3]);
      pb.u[2] = cvtpk(p[2 * kc + 1][0], p[2 * kc + 1][1]);
      pb.u[3] = cvtpk(p[2 * kc + 1][2], p[2 * kc + 1][3]);
      const int chb = ((kc * 4 + g) ^ c) << 4;
      bf16x8 av;
      av = *(const bf16x8*)(vROb + chb);
      o0 = __builtin_amdgcn_mfma_f32_16x16x32_bf16(av, pb.v, o0, 0, 0, 0);
      av = *(const bf16x8*)(vROb + 4096 + chb);
      o1 = __builtin_amdgcn_mfma_f32_16x16x32_bf16(av, pb.v, o1, 0, 0, 0);
      av = *(const bf16x8*)(vROb + 8192 + chb);
      o2 = __builtin_amdgcn_mfma_f32_16x16x32_bf16(av, pb.v, o2, 0, 0, 0);
    }
    __builtin_amdgcn_s_setprio(0);
  }
#undef ASTAGE

  // epilogue: lsum = O^T[d=40][c] (V ones-row), lives in o2[0] of lane 32+c
  const float lsum = __shfl(o2[0], 32 + c);
  const float inv = 1.0f / lsum;
  unsigned short* orow = AO + (size_t)(b * SEQ + qrow0 + c) * CH + h * HD;
  union { uint2 q; unsigned u[2]; } st;
  st.u[0] = cvtpk(o0[0] * inv, o0[1] * inv);
  st.u[1] = cvtpk(o0[2] * inv, o0[3] * inv);
  *(uint2*)(orow + g * 4) = st.q;
  st.u[0] = cvtpk(o1[0] * inv, o1[1] * inv);
  st.u[1] = cvtpk(o1[2] * inv, o1[3] * inv);
  *(uint2*)(orow + 16 + g * 4) = st.q;
  if (g < 2) {
    st.u[0] = cvtpk(o2[0] * inv, o2[1] * inv);
    st.u[1] = cvtpk(o2[2] * inv, o2[3] * inv);
    *(uint2*)(orow + 32 + g * 4) = st.q;
  }
}

// ---------------------------------------------------------------------------
// Output projection: A = AO bf16 (reg-staged), W = Wo f32 (reg-staged + cvt),
// out f32 [m][CH] + bias. Tile 64x64, grid (256,5).
// ---------------------------------------------------------------------------
__global__ __launch_bounds__(256)
void o_proj(const unsigned short* __restrict__ AO, const float* __restrict__ Wo,
            const float* __restrict__ bias, float* __restrict__ out) {
  __shared__ unsigned short Al[64][64];
  __shared__ unsigned short Bl[64][64];

  const int tid = threadIdx.x;
  const int w = tid >> 6, l = tid & 63, g = l >> 4, c = l & 15;
  const int wm = w >> 1, wn = w & 1;
  const int mb = blockIdx.x, nb = blockIdx.y;

  const int sr = tid >> 3, ch = tid & 7;
  const int pc = ch ^ (sr & 7);
  const unsigned short* aB = AO + (size_t)(mb * 64) * CH + ch * 8;
  const float* wB = Wo + (size_t)(nb * 64) * CH + ch * 8;
  unsigned short* dA0 = &Al[sr][pc * 8];
  unsigned short* dA1 = &Al[sr + 32][pc * 8];
  unsigned short* dB0 = &Bl[sr][pc * 8];
  unsigned short* dB1 = &Bl[sr + 32][pc * 8];

  bf16x8 qa0, qa1;
  float4 rw0, rw1, rw2, rw3;
#define OLOAD(kb)                                                              \
  {                                                                            \
    qa0 = *(const bf16x8*)(aB + (size_t)sr * CH + (kb));                       \
    qa1 = *(const bf16x8*)(aB + (size_t)(sr + 32) * CH + (kb));                \
    rw0 = *(const float4*)(wB + (size_t)sr * CH + (kb));                       \
    rw1 = *(const float4*)(wB + (size_t)sr * CH + (kb) + 4);                   \
    rw2 = *(const float4*)(wB + (size_t)(sr + 32) * CH + (kb));                \
    rw3 = *(const float4*)(wB + (size_t)(sr + 32) * CH + (kb) + 4);            \
  }

  f32x4 acc[2][2] = {};
  OLOAD(0);
#pragma unroll
  for (int t = 0; t < 5; ++t) {
    __syncthreads();
    *(bf16x8*)dA0 = qa0;
    *(bf16x8*)dA1 = qa1;
    {
      union { bf16x8 v; unsigned u[4]; } pk_;
      pk_.u[0] = cvtpk(rw0.x, rw0.y); pk_.u[1] = cvtpk(rw0.z, rw0.w);
      pk_.u[2] = cvtpk(rw1.x, rw1.y); pk_.u[3] = cvtpk(rw1.z, rw1.w);
      *(bf16x8*)dB0 = pk_.v;
      pk_.u[0] = cvtpk(rw2.x, rw2.y); pk_.u[1] = cvtpk(rw2.z, rw2.w);
      pk_.u[2] = cvtpk(rw3.x, rw3.y); pk_.u[3] = cvtpk(rw3.z, rw3.w);
      *(bf16x8*)dB1 = pk_.v;
    }
    __syncthreads();
    if (t < 4) OLOAD((t + 1) * 64);
#pragma unroll
    for (int kc = 0; kc < 2; ++kc) {
      bf16x8 a0 = lds_frag(&Al[0][0], wm * 32 + c,      kc * 4 + g);
      bf16x8 a1 = lds_frag(&Al[0][0], wm * 32 + 16 + c, kc * 4 + g);
      bf16x8 b0 = lds_frag(&Bl[0][0], wn * 32 + c,      kc * 4 + g);
      bf16x8 b1 = lds_frag(&Bl[0][0], wn * 32 + 16 + c, kc * 4 + g);
      acc[0][0] = __builtin_amdgcn_mfma_f32_16x16x32_bf16(a0, b0, acc[0][0], 0, 0, 0);
      acc[0][1] = __builtin_amdgcn_mfma_f32_16x16x32_bf16(a0, b1, acc[0][1], 0, 0, 0);
      acc[1][0] = __builtin_amdgcn_mfma_f32_16x16x32_bf16(a1, b0, acc[1][0], 0, 0, 0);
      acc[1][1] = __builtin_amdgcn_mfma_f32_16x16x32_bf16(a1, b1, acc[1][1], 0, 0, 0);
    }
  }
#undef OLOAD

#pragma unroll
  for (int i = 0; i < 2; ++i)
#pragma unroll
    for (int j = 0; j < 2; ++j)
#pragma unroll
      for (int r = 0; r < 4; ++r) {
        const int m = mb * 64 + wm * 32 + i * 16 + g * 4 + r;
        const int n = nb * 64 + wn * 32 + j * 16 + c;
        out[(size_t)m * CH + n] = acc[i][j][r] + bias[n];
      }
}

// ---------------------------------------------------------------------------
extern "C" void kernel_launch(void* const* d_in, const int* in_sizes, int n_in,
                              void* d_out, int out_size, void* d_ws, size_t ws_size,
                              hipStream_t stream) {
  const float* hs = (const float*)d_in[0];
  const float* Wq = (const float*)d_in[1];
  const float* Wk = (const float*)d_in[2];
  const float* Wv = (const float*)d_in[3];
  const float* Wo = (const float*)d_in[4];
  const float* bo = (const float*)d_in[5];
  const int* kptr = (const int*)d_in[7];
  float* out = (float*)d_out;

  unsigned short* Qs = (unsigned short*)d_ws;       // [16384][320] bf16
  unsigned short* Kp = Qs + HS_N;                   // [8][1024][48]
  unsigned short* Vt = Kp + NH * SEQ * KPD;         // [8][48][1024]
  unsigned short* AO = Vt + NH * KPD * SEQ;         // [16384][320]

  qkv_proj<<<dim3(1440), dim3(256), 0, stream>>>(hs, Wq, Wk, Wv, kptr, Qs, Kp, Vt);
  attn7<<<dim3(1024), dim3(512), 0, stream>>>(Qs, Kp, Vt, AO);
  o_proj<<<dim3(256, 5), dim3(256), 0, stream>>>(AO, Wo, bo, out);
}